// Round 1
// baseline (1887.960 us; speedup 1.0000x reference)
//
#include <hip/hip_runtime.h>
#include <hip/hip_bf16.h>
#include <cstdint>
#include <math.h>

// Problem dims (fixed)
#define BB 2
#define TT 2048
#define DD 4096
#define HQ 32
#define HKV 8
#define DK 128
#define MM (BB*TT)          // 4096 rows
#define NQ (HQ*DK)          // 4096
#define NKV (HKV*DK)        // 1024

typedef __attribute__((ext_vector_type(8))) short short8;
typedef __attribute__((ext_vector_type(4))) float floatx4;

__device__ inline uint16_t f2bf(float f) {
    uint32_t u = __float_as_uint(f);
    uint32_t r = (u + 0x7fffu + ((u >> 16) & 1u)) >> 16;
    return (uint16_t)r;
}

// ---------------- RoPE tables: cos/sin [2048][64] ----------------
__global__ void rope_tables_k(float* __restrict__ cosT, float* __restrict__ sinT) {
    int t = blockIdx.x;        // 0..2047
    int d = threadIdx.x;       // 0..63
    // theta = 10000^(-d/64)
    float theta = expf(-(float)d * (9.210340371976184f / 64.0f));
    float arg = (float)t * theta;
    float s, c;
    sincosf(arg, &s, &c);
    cosT[t * 64 + d] = c;
    sinT[t * 64 + d] = s;
}

// ------------- transpose-convert weights: W (K x N fp32) -> WT (N x K bf16) -------------
__global__ void wconv_k(const float* __restrict__ W, uint16_t* __restrict__ WT, int K, int N) {
    __shared__ float tile[32][33];
    int n0 = blockIdx.x * 32, k0 = blockIdx.y * 32;
    int tx = threadIdx.x, ty = threadIdx.y;  // (32, 8)
#pragma unroll
    for (int i = 0; i < 4; i++) {
        int r = k0 + ty + i * 8;
        tile[ty + i * 8][tx] = W[(size_t)r * N + n0 + tx];
    }
    __syncthreads();
#pragma unroll
    for (int i = 0; i < 4; i++) {
        int r = n0 + ty + i * 8;
        WT[(size_t)r * K + k0 + tx] = f2bf(tile[tx][ty + i * 8]);
    }
}

// ------------- activation convert fp32 -> bf16 (flat) -------------
__global__ void aconv_k(const float4* __restrict__ X, uint2* __restrict__ Y, int n4) {
    int i = blockIdx.x * blockDim.x + threadIdx.x;
    if (i < n4) {
        float4 v = X[i];
        uint2 o;
        o.x = (uint32_t)f2bf(v.x) | ((uint32_t)f2bf(v.y) << 16);
        o.y = (uint32_t)f2bf(v.z) | ((uint32_t)f2bf(v.w) << 16);
        Y[i] = o;
    }
}

// ------------- GEMM: C = A(MxK,bf16,K-major) * B(NxK,bf16,K-major)^T -------------
// Block 256 thr = 4 waves. Tile BM=128,BN=128,BK=64. Wave w: rows [w*32,w*32+32), all 128 cols.
// EPI: 1=Q(rope->bf16), 2=K(rope->bf16 + fp32 cache), 3=V(bf16 + fp32 cache), 4=fp32 out
template <int EPI>
__global__ __launch_bounds__(256) void gemm_k(
    const uint16_t* __restrict__ A, const uint16_t* __restrict__ Bm,
    int M, int N, int K,
    uint16_t* __restrict__ Obf, float* __restrict__ Ofp,
    const float* __restrict__ cosT, const float* __restrict__ sinT)
{
    __shared__ __attribute__((aligned(16))) uint16_t As[128 * 72];
    __shared__ __attribute__((aligned(16))) uint16_t Bs[128 * 72];
    int m0 = blockIdx.y * 128;
    int n0 = blockIdx.x * 128;
    int tid = threadIdx.x;
    int lane = tid & 63, wave = tid >> 6;
    int l15 = lane & 15, quad = lane >> 4;

    floatx4 acc[2][8];
#pragma unroll
    for (int a = 0; a < 2; a++)
#pragma unroll
        for (int b = 0; b < 8; b++) acc[a][b] = floatx4{0.f, 0.f, 0.f, 0.f};

    for (int k0 = 0; k0 < K; k0 += 64) {
        short8 ra[4], rb[4];
#pragma unroll
        for (int i = 0; i < 4; i++) {
            int chunk = tid + i * 256;
            int row = chunk >> 3, kc = chunk & 7;
            ra[i] = *(const short8*)(A + (size_t)(m0 + row) * K + k0 + kc * 8);
            rb[i] = *(const short8*)(Bm + (size_t)(n0 + row) * K + k0 + kc * 8);
        }
        __syncthreads();
#pragma unroll
        for (int i = 0; i < 4; i++) {
            int chunk = tid + i * 256;
            int row = chunk >> 3, kc = chunk & 7;
            *(short8*)(As + row * 72 + kc * 8) = ra[i];
            *(short8*)(Bs + row * 72 + kc * 8) = rb[i];
        }
        __syncthreads();
#pragma unroll
        for (int ks = 0; ks < 2; ks++) {
            short8 af[2], bf[8];
#pragma unroll
            for (int mt = 0; mt < 2; mt++)
                af[mt] = *(const short8*)(As + (wave * 32 + mt * 16 + l15) * 72 + ks * 32 + quad * 8);
#pragma unroll
            for (int nt = 0; nt < 8; nt++)
                bf[nt] = *(const short8*)(Bs + (nt * 16 + l15) * 72 + ks * 32 + quad * 8);
#pragma unroll
            for (int mt = 0; mt < 2; mt++)
#pragma unroll
                for (int nt = 0; nt < 8; nt++)
                    acc[mt][nt] = __builtin_amdgcn_mfma_f32_16x16x32_bf16(af[mt], bf[nt], acc[mt][nt], 0, 0, 0);
        }
    }

    // Epilogue. C layout: row = quad*4+reg (+ wave*32 + mt*16), col = l15 + nt*16.
#pragma unroll
    for (int mt = 0; mt < 2; mt++) {
        int rbase = m0 + wave * 32 + mt * 16 + quad * 4;
        if (EPI == 4) {
#pragma unroll
            for (int nt = 0; nt < 8; nt++) {
                int c = n0 + nt * 16 + l15;
#pragma unroll
                for (int r = 0; r < 4; r++)
                    Ofp[(size_t)(rbase + r) * N + c] = acc[mt][nt][r];
            }
        } else if (EPI == 3) {  // V: bf16 vh + fp32 cache[...,128+d]
            int h = n0 >> 7;
#pragma unroll
            for (int nt = 0; nt < 8; nt++) {
                int cb = nt * 16 + l15;  // d in 0..127
#pragma unroll
                for (int r = 0; r < 4; r++) {
                    int row = rbase + r;
                    float v = acc[mt][nt][r];
                    Obf[(size_t)row * N + n0 + cb] = f2bf(v);
                    Ofp[((size_t)row * 8 + h) * 256 + 128 + cb] = v;
                }
            }
        } else {  // Q / K with RoPE: pairs (cb, cb+64) share theta index cb
            int h = n0 >> 7;
#pragma unroll
            for (int nt = 0; nt < 4; nt++) {
                int cb = nt * 16 + l15;  // 0..63
#pragma unroll
                for (int r = 0; r < 4; r++) {
                    int row = rbase + r;
                    int t = row & (TT - 1);
                    float cs = cosT[t * 64 + cb];
                    float sn = sinT[t * 64 + cb];
                    float x1 = acc[mt][nt][r], x2 = acc[mt][nt + 4][r];
                    float o1 = x1 * cs - x2 * sn;
                    float o2 = x2 * cs + x1 * sn;
                    Obf[(size_t)row * N + n0 + cb] = f2bf(o1);
                    Obf[(size_t)row * N + n0 + cb + 64] = f2bf(o2);
                    if (EPI == 2) {
                        Ofp[((size_t)row * 8 + h) * 256 + cb] = o1;
                        Ofp[((size_t)row * 8 + h) * 256 + cb + 64] = o2;
                    }
                }
            }
        }
    }
}

// ------------- transpose v_heads: vh[b*2048+t][h*128+d] -> vT[(b*8+h)*128+d][t] -------------
__global__ void vtrans_k(const uint16_t* __restrict__ vh, uint16_t* __restrict__ vT) {
    __shared__ uint16_t tile[32][33];
    int bh = blockIdx.z;           // b*8+h
    int t0 = blockIdx.x * 32;
    int d0 = blockIdx.y * 32;
    int b = bh >> 3, h = bh & 7;
    int tx = threadIdx.x, ty = threadIdx.y;
#pragma unroll
    for (int i = 0; i < 4; i++) {
        int t = t0 + ty + i * 8;
        tile[ty + i * 8][tx] = vh[(size_t)(b * TT + t) * NKV + h * DK + d0 + tx];
    }
    __syncthreads();
#pragma unroll
    for (int i = 0; i < 4; i++) {
        int d = d0 + ty + i * 8;
        vT[((size_t)bh * DK + d) * TT + t0 + tx] = tile[tx][ty + i * 8];
    }
}

// ------------- flash attention: per-wave 16 q rows, 32-key tiles, online softmax -------------
__global__ __launch_bounds__(256) void attn_k(
    const uint16_t* __restrict__ qh, const uint16_t* __restrict__ kh,
    const uint16_t* __restrict__ vT, uint16_t* __restrict__ ob)
{
    int tid = threadIdx.x;
    int lane = tid & 63, wave = tid >> 6;
    int l15 = lane & 15, quad = lane >> 4;
    int qt = blockIdx.x;   // 0..31 (64-row q tiles)
    int hq = blockIdx.y;   // 0..31
    int b = blockIdx.z;    // 0..1
    int h = hq & 7;
    int qbase = qt * 64 + wave * 16;  // t index of first q row for this wave

    __shared__ __attribute__((aligned(16))) uint16_t Pl[4][16 * 40];
    uint16_t* P = &Pl[wave][0];

    // Q fragments (A-layout): lane holds q[qbase+l15][ks*32 + quad*8 + j]
    short8 qf[4];
    const uint16_t* qrow = qh + (size_t)(b * TT + qbase + l15) * NQ + hq * DK;
#pragma unroll
    for (int ks = 0; ks < 4; ks++)
        qf[ks] = *(const short8*)(qrow + ks * 32 + quad * 8);

    floatx4 O[8];
#pragma unroll
    for (int i = 0; i < 8; i++) O[i] = floatx4{0.f, 0.f, 0.f, 0.f};
    float mrow[4], lrow[4];
#pragma unroll
    for (int r = 0; r < 4; r++) { mrow[r] = -INFINITY; lrow[r] = 0.0f; }

    const float scale = 0.08838834764831845f;  // 1/sqrt(128)
    int qmax = qbase + 15;
    const uint16_t* kbase = kh + (size_t)(b * TT) * NKV + h * DK;
    const uint16_t* vbase = vT + ((size_t)(b * 8 + h) * DK) * TT;

    for (int kb0 = 0; kb0 <= qmax; kb0 += 32) {
        floatx4 s[2];
        s[0] = floatx4{0.f, 0.f, 0.f, 0.f};
        s[1] = floatx4{0.f, 0.f, 0.f, 0.f};
#pragma unroll
        for (int ks = 0; ks < 4; ks++) {
#pragma unroll
            for (int nt = 0; nt < 2; nt++) {
                short8 kf = *(const short8*)(kbase + (size_t)(kb0 + nt * 16 + l15) * NKV + ks * 32 + quad * 8);
                s[nt] = __builtin_amdgcn_mfma_f32_16x16x32_bf16(qf[ks], kf, s[nt], 0, 0, 0);
            }
        }
        // scale + causal mask + online softmax (rows r = qbase+quad*4+reg, key = kb0+nt*16+l15)
        float p0[4], p1[4], alpha[4];
#pragma unroll
        for (int r = 0; r < 4; r++) {
            int row = qbase + quad * 4 + r;
            float v0 = s[0][r] * scale;
            float v1 = s[1][r] * scale;
            if (kb0 + l15 > row) v0 = -INFINITY;
            if (kb0 + 16 + l15 > row) v1 = -INFINITY;
            float mx = fmaxf(v0, v1);
            mx = fmaxf(mx, __shfl_xor(mx, 1));
            mx = fmaxf(mx, __shfl_xor(mx, 2));
            mx = fmaxf(mx, __shfl_xor(mx, 4));
            mx = fmaxf(mx, __shfl_xor(mx, 8));
            float mnew = fmaxf(mrow[r], mx);
            alpha[r] = __expf(mrow[r] - mnew);
            float e0 = __expf(v0 - mnew);
            float e1 = __expf(v1 - mnew);
            p0[r] = e0; p1[r] = e1;
            float sum = e0 + e1;
            sum += __shfl_xor(sum, 1);
            sum += __shfl_xor(sum, 2);
            sum += __shfl_xor(sum, 4);
            sum += __shfl_xor(sum, 8);
            lrow[r] = lrow[r] * alpha[r] + sum;
            mrow[r] = mnew;
        }
#pragma unroll
        for (int vt = 0; vt < 8; vt++)
#pragma unroll
            for (int r = 0; r < 4; r++) O[vt][r] *= alpha[r];
        // P: C-layout -> LDS (16 rows x 32 keys, row stride 40), then read as A-frag
#pragma unroll
        for (int r = 0; r < 4; r++) {
            P[(quad * 4 + r) * 40 + l15] = f2bf(p0[r]);
            P[(quad * 4 + r) * 40 + 16 + l15] = f2bf(p1[r]);
        }
        short8 pf = *(const short8*)(P + l15 * 40 + quad * 8);
#pragma unroll
        for (int vt = 0; vt < 8; vt++) {
            short8 vf = *(const short8*)(vbase + (size_t)(vt * 16 + l15) * TT + kb0 + quad * 8);
            O[vt] = __builtin_amdgcn_mfma_f32_16x16x32_bf16(pf, vf, O[vt], 0, 0, 0);
        }
    }
    // write attention out (bf16), channel = hq*128 + v
#pragma unroll
    for (int r = 0; r < 4; r++) {
        float inv = 1.0f / lrow[r];
        int row = b * TT + qbase + quad * 4 + r;
#pragma unroll
        for (int vt = 0; vt < 8; vt++)
            ob[(size_t)row * NQ + hq * DK + vt * 16 + l15] = f2bf(O[vt][r] * inv);
    }
}

extern "C" void kernel_launch(void* const* d_in, const int* in_sizes, int n_in,
                              void* d_out, int out_size, void* d_ws, size_t ws_size,
                              hipStream_t stream)
{
    const float* q  = (const float*)d_in[0];
    const float* k  = (const float*)d_in[1];
    const float* v  = (const float*)d_in[2];
    const float* wq = (const float*)d_in[3];
    const float* wk = (const float*)d_in[4];
    const float* wv = (const float*)d_in[5];
    const float* wo = (const float*)d_in[6];
    float* out   = (float*)d_out;                       // [2,2048,4096]
    float* cache = out + (size_t)MM * DD;               // [2,2048,8,256]

    char* ws = (char*)d_ws;
    float* cosT = (float*)ws;
    float* sinT = cosT + TT * 64;
    size_t off = 1u << 20;  // 1 MB
    const size_t SZ32 = (size_t)MM * DD * 2;   // 32 MB (bf16 4096x4096)
    const size_t SZ8  = (size_t)MM * NKV * 2;  // 8 MB  (bf16 4096x1024)
    uint16_t* wqT = (uint16_t*)(ws + off); off += SZ32;   // 4096x4096
    uint16_t* wkT = (uint16_t*)(ws + off); off += SZ8;    // 1024x4096
    uint16_t* wvT = (uint16_t*)(ws + off); off += SZ8;    // 1024x4096
    uint16_t* qb  = (uint16_t*)(ws + off); off += SZ32;
    uint16_t* kb  = (uint16_t*)(ws + off); off += SZ32;
    uint16_t* vb  = (uint16_t*)(ws + off); off += SZ32;
    uint16_t* khB = (uint16_t*)(ws + off); off += SZ8;
    uint16_t* vhB = (uint16_t*)(ws + off); off += SZ8;
    // aliases (stream-ordered reuse):
    uint16_t* vTr = wvT;  // after V GEMM done with wvT
    uint16_t* qhB = vb;   // after V GEMM done with vb
    uint16_t* woT = kb;   // after K GEMM done with kb
    uint16_t* obf = qb;   // after Q GEMM done with qb

    // 1. RoPE tables
    rope_tables_k<<<TT, 64, 0, stream>>>(cosT, sinT);
    // 2. weight convert/transpose (wq, wk, wv)
    wconv_k<<<dim3(NQ / 32, DD / 32), dim3(32, 8), 0, stream>>>(wq, wqT, DD, NQ);
    wconv_k<<<dim3(NKV / 32, DD / 32), dim3(32, 8), 0, stream>>>(wk, wkT, DD, NKV);
    wconv_k<<<dim3(NKV / 32, DD / 32), dim3(32, 8), 0, stream>>>(wv, wvT, DD, NKV);
    // 3. activation converts
    int n4 = MM * DD / 4;
    aconv_k<<<(n4 + 255) / 256, 256, 0, stream>>>((const float4*)q, (uint2*)qb, n4);
    aconv_k<<<(n4 + 255) / 256, 256, 0, stream>>>((const float4*)k, (uint2*)kb, n4);
    aconv_k<<<(n4 + 255) / 256, 256, 0, stream>>>((const float4*)v, (uint2*)vb, n4);
    // 4. V GEMM (writes vh bf16 + cache fp32)
    gemm_k<3><<<dim3(NKV / 128, MM / 128), 256, 0, stream>>>(vb, wvT, MM, NKV, DD, vhB, cache, cosT, sinT);
    // 5. K GEMM (RoPE; writes kh bf16 + cache fp32)
    gemm_k<2><<<dim3(NKV / 128, MM / 128), 256, 0, stream>>>(kb, wkT, MM, NKV, DD, khB, cache, cosT, sinT);
    // 6. Q GEMM (RoPE; writes qh bf16 into vb's space)
    gemm_k<1><<<dim3(NQ / 128, MM / 128), 256, 0, stream>>>(qb, wqT, MM, NQ, DD, qhB, nullptr, cosT, sinT);
    // 7. wo convert (into kb's space)
    wconv_k<<<dim3(DD / 32, DD / 32), dim3(32, 8), 0, stream>>>(wo, woT, DD, DD);
    // 8. V transpose (into wvT's space)
    vtrans_k<<<dim3(TT / 32, DK / 32, BB * HKV), dim3(32, 8), 0, stream>>>(vhB, vTr);
    // 9. attention (into qb's space)
    attn_k<<<dim3(TT / 64, HQ, BB), 256, 0, stream>>>(qhB, khB, vTr, obf);
    // 10. output projection -> fp32 out
    gemm_k<4><<<dim3(DD / 128, MM / 128), 256, 0, stream>>>(obf, woT, MM, DD, DD, nullptr, out, cosT, sinT);
}

// Round 2
// 1166.913 us; speedup vs baseline: 1.6179x; 1.6179x over previous
//
#include <hip/hip_runtime.h>
#include <hip/hip_bf16.h>
#include <cstdint>
#include <math.h>

// Problem dims (fixed)
#define BB 2
#define TT 2048
#define DD 4096
#define HQ 32
#define HKV 8
#define DK 128
#define MM (BB*TT)          // 4096 rows
#define NQ (HQ*DK)          // 4096
#define NKV (HKV*DK)        // 1024

typedef __attribute__((ext_vector_type(8))) short short8;
typedef __attribute__((ext_vector_type(4))) short bshort4;
typedef __attribute__((ext_vector_type(4))) float floatx4;

__device__ inline uint16_t f2bf(float f) {
    uint32_t u = __float_as_uint(f);
    uint32_t r = (u + 0x7fffu + ((u >> 16) & 1u)) >> 16;
    return (uint16_t)r;
}

// ---------------- RoPE tables: cos/sin [2048][64] ----------------
__global__ void rope_tables_k(float* __restrict__ cosT, float* __restrict__ sinT) {
    int t = blockIdx.x;        // 0..2047
    int d = threadIdx.x;       // 0..63
    float theta = expf(-(float)d * (9.210340371976184f / 64.0f));
    float arg = (float)t * theta;
    float s, c;
    sincosf(arg, &s, &c);
    cosT[t * 64 + d] = c;
    sinT[t * 64 + d] = s;
}

// ------------- transpose-convert weights: W (K x N fp32) -> WT (N x K bf16) -------------
__global__ void wconv_k(const float* __restrict__ W, uint16_t* __restrict__ WT, int K, int N) {
    __shared__ float tile[32][33];
    int n0 = blockIdx.x * 32, k0 = blockIdx.y * 32;
    int tx = threadIdx.x, ty = threadIdx.y;  // (32, 8)
#pragma unroll
    for (int i = 0; i < 4; i++) {
        int r = k0 + ty + i * 8;
        tile[ty + i * 8][tx] = W[(size_t)r * N + n0 + tx];
    }
    __syncthreads();
#pragma unroll
    for (int i = 0; i < 4; i++) {
        int r = n0 + ty + i * 8;
        WT[(size_t)r * K + k0 + tx] = f2bf(tile[tx][ty + i * 8]);
    }
}

// ------------- activation convert fp32 -> bf16 (flat) -------------
__global__ void aconv_k(const float4* __restrict__ X, uint2* __restrict__ Y, int n4) {
    int i = blockIdx.x * blockDim.x + threadIdx.x;
    if (i < n4) {
        float4 v = X[i];
        uint2 o;
        o.x = (uint32_t)f2bf(v.x) | ((uint32_t)f2bf(v.y) << 16);
        o.y = (uint32_t)f2bf(v.z) | ((uint32_t)f2bf(v.w) << 16);
        Y[i] = o;
    }
}

// ------------- GEMM: C = A(MxK,bf16,K-major) * B(NxK,bf16,K-major)^T -------------
// EPI: 1=Q(rope->bf16), 2=K(rope->bf16 + fp32 cache), 3=V(bf16 + fp32 cache), 4=fp32 out
template <int EPI>
__global__ __launch_bounds__(256) void gemm_k(
    const uint16_t* __restrict__ A, const uint16_t* __restrict__ Bm,
    int M, int N, int K,
    uint16_t* __restrict__ Obf, float* __restrict__ Ofp,
    const float* __restrict__ cosT, const float* __restrict__ sinT)
{
    __shared__ __attribute__((aligned(16))) uint16_t As[128 * 72];
    __shared__ __attribute__((aligned(16))) uint16_t Bs[128 * 72];
    int m0 = blockIdx.y * 128;
    int n0 = blockIdx.x * 128;
    int tid = threadIdx.x;
    int lane = tid & 63, wave = tid >> 6;
    int l15 = lane & 15, quad = lane >> 4;

    floatx4 acc[2][8];
#pragma unroll
    for (int a = 0; a < 2; a++)
#pragma unroll
        for (int b = 0; b < 8; b++) acc[a][b] = floatx4{0.f, 0.f, 0.f, 0.f};

    for (int k0 = 0; k0 < K; k0 += 64) {
        short8 ra[4], rb[4];
#pragma unroll
        for (int i = 0; i < 4; i++) {
            int chunk = tid + i * 256;
            int row = chunk >> 3, kc = chunk & 7;
            ra[i] = *(const short8*)(A + (size_t)(m0 + row) * K + k0 + kc * 8);
            rb[i] = *(const short8*)(Bm + (size_t)(n0 + row) * K + k0 + kc * 8);
        }
        __syncthreads();
#pragma unroll
        for (int i = 0; i < 4; i++) {
            int chunk = tid + i * 256;
            int row = chunk >> 3, kc = chunk & 7;
            *(short8*)(As + row * 72 + kc * 8) = ra[i];
            *(short8*)(Bs + row * 72 + kc * 8) = rb[i];
        }
        __syncthreads();
#pragma unroll
        for (int ks = 0; ks < 2; ks++) {
            short8 af[2], bf[8];
#pragma unroll
            for (int mt = 0; mt < 2; mt++)
                af[mt] = *(const short8*)(As + (wave * 32 + mt * 16 + l15) * 72 + ks * 32 + quad * 8);
#pragma unroll
            for (int nt = 0; nt < 8; nt++)
                bf[nt] = *(const short8*)(Bs + (nt * 16 + l15) * 72 + ks * 32 + quad * 8);
#pragma unroll
            for (int mt = 0; mt < 2; mt++)
#pragma unroll
                for (int nt = 0; nt < 8; nt++)
                    acc[mt][nt] = __builtin_amdgcn_mfma_f32_16x16x32_bf16(af[mt], bf[nt], acc[mt][nt], 0, 0, 0);
        }
    }

    // Epilogue. C layout: row = quad*4+reg (+ wave*32 + mt*16), col = l15 + nt*16.
#pragma unroll
    for (int mt = 0; mt < 2; mt++) {
        int rbase = m0 + wave * 32 + mt * 16 + quad * 4;
        if (EPI == 4) {
#pragma unroll
            for (int nt = 0; nt < 8; nt++) {
                int c = n0 + nt * 16 + l15;
#pragma unroll
                for (int r = 0; r < 4; r++)
                    Ofp[(size_t)(rbase + r) * N + c] = acc[mt][nt][r];
            }
        } else if (EPI == 3) {  // V: bf16 vh + fp32 cache[...,128+d]
            int h = n0 >> 7;
#pragma unroll
            for (int nt = 0; nt < 8; nt++) {
                int cb = nt * 16 + l15;  // d in 0..127
#pragma unroll
                for (int r = 0; r < 4; r++) {
                    int row = rbase + r;
                    float v = acc[mt][nt][r];
                    Obf[(size_t)row * N + n0 + cb] = f2bf(v);
                    Ofp[((size_t)row * 8 + h) * 256 + 128 + cb] = v;
                }
            }
        } else {  // Q / K with RoPE: pairs (cb, cb+64) share theta index cb
            int h = n0 >> 7;
#pragma unroll
            for (int nt = 0; nt < 4; nt++) {
                int cb = nt * 16 + l15;  // 0..63
#pragma unroll
                for (int r = 0; r < 4; r++) {
                    int row = rbase + r;
                    int t = row & (TT - 1);
                    float cs = cosT[t * 64 + cb];
                    float sn = sinT[t * 64 + cb];
                    float x1 = acc[mt][nt][r], x2 = acc[mt][nt + 4][r];
                    float o1 = x1 * cs - x2 * sn;
                    float o2 = x2 * cs + x1 * sn;
                    Obf[(size_t)row * N + n0 + cb] = f2bf(o1);
                    Obf[(size_t)row * N + n0 + cb + 64] = f2bf(o2);
                    if (EPI == 2) {
                        Ofp[((size_t)row * 8 + h) * 256 + cb] = o1;
                        Ofp[((size_t)row * 8 + h) * 256 + cb + 64] = o2;
                    }
                }
            }
        }
    }
}

// ------------- transpose v_heads: vh[b*2048+t][h*128+d] -> vT[(b*8+h)*128+d][t] -------------
__global__ void vtrans_k(const uint16_t* __restrict__ vh, uint16_t* __restrict__ vT) {
    __shared__ uint16_t tile[32][33];
    int bh = blockIdx.z;           // b*8+h
    int t0 = blockIdx.x * 32;
    int d0 = blockIdx.y * 32;
    int b = bh >> 3, h = bh & 7;
    int tx = threadIdx.x, ty = threadIdx.y;
#pragma unroll
    for (int i = 0; i < 4; i++) {
        int t = t0 + ty + i * 8;
        tile[ty + i * 8][tx] = vh[(size_t)(b * TT + t) * NKV + h * DK + d0 + tx];
    }
    __syncthreads();
#pragma unroll
    for (int i = 0; i < 4; i++) {
        int d = d0 + ty + i * 8;
        vT[((size_t)bh * DK + d) * TT + t0 + tx] = tile[tx][ty + i * 8];
    }
}

// ------------- flash attention v2 -------------
// Block = 4 waves = the 4 Q heads of one KV group. Each wave: 32 Q rows (2 col-tiles).
// K tile (32x128) and V^T tile (128x32) staged in LDS, shared by all 4 waves.
// S^T computed via swapped MFMA operands (A=K rows=keys, B=Q cols=qrows) so softmax
// state is per-lane (l15 = qrow); reductions are 2 shfl_xor over the quad dim.
// Causal balancing: block x processes Q-tile pair (x, 63-x) -> 65 key-tiles/block.
__global__ __launch_bounds__(256) void attn_k(
    const uint16_t* __restrict__ qh, const uint16_t* __restrict__ kh,
    const uint16_t* __restrict__ vT, uint16_t* __restrict__ ob)
{
    __shared__ __attribute__((aligned(16))) uint16_t Ks[32 * 136];   // [key][d], pad 8
    __shared__ __attribute__((aligned(16))) uint16_t Vs[128 * 40];   // [dv][key], pad 8
    __shared__ __attribute__((aligned(16))) uint16_t Ps[4 * 32 * 40];// per-wave P [qrow][key]

    int tid = threadIdx.x;
    int lane = tid & 63, wave = tid >> 6;
    int l15 = lane & 15, quad = lane >> 4;
    int kvh = blockIdx.y;
    int b = blockIdx.z;
    int hq = wave * 8 + kvh;            // G*8+H mapping: Q heads of group = {kvh, kvh+8, +16, +24}
    uint16_t* P = Ps + wave * (32 * 40);

    const uint16_t* kbase = kh + (size_t)(b * TT) * NKV + kvh * DK;
    const uint16_t* vbase = vT + ((size_t)(b * 8 + kvh) * DK) * TT;
    const float scale2 = 0.08838834764831845f * 1.4426950408889634f;  // 1/sqrt(128) * log2(e)

    int kkey = tid >> 4, kdc = tid & 15;   // K staging: 16 keys/round x 16B chunks
    int vdv = tid >> 2, vtc = tid & 3;     // V staging: 64 dv/round x 8B... (16B chunks of keys)

    for (int half = 0; half < 2; half++) {
        int hh = half ? (63 - (int)blockIdx.x) : (int)blockIdx.x;
        int q0 = hh * 32;
        int ntiles = hh + 1;

        // Q B-frags (x32 B-layout: lane l15 = qrow, k = ks*32 + quad*8 + j)
        short8 qf[2][4];
#pragma unroll
        for (int qc = 0; qc < 2; qc++) {
            const uint16_t* qr = qh + (size_t)(b * TT + q0 + qc * 16 + l15) * NQ + hq * DK;
#pragma unroll
            for (int ks = 0; ks < 4; ks++)
                qf[qc][ks] = *(const short8*)(qr + ks * 32 + quad * 8);
        }

        floatx4 O[2][8];
#pragma unroll
        for (int qc = 0; qc < 2; qc++)
#pragma unroll
            for (int vt = 0; vt < 8; vt++) O[qc][vt] = floatx4{0.f, 0.f, 0.f, 0.f};
        float m_[2] = {-INFINITY, -INFINITY};
        float l_[2] = {0.f, 0.f};

        // prefetch tile 0 into regs
        short8 kst[2], vst[2];
#pragma unroll
        for (int i = 0; i < 2; i++) {
            kst[i] = *(const short8*)(kbase + (size_t)(kkey + i * 16) * NKV + kdc * 8);
            vst[i] = *(const short8*)(vbase + (size_t)(vdv + i * 64) * TT + vtc * 8);
        }

        for (int t = 0; t < ntiles; t++) {
            int kb0 = t * 32;
            __syncthreads();   // previous tile's LDS readers done
#pragma unroll
            for (int i = 0; i < 2; i++) {
                *(short8*)(Ks + (kkey + i * 16) * 136 + kdc * 8) = kst[i];
                *(short8*)(Vs + (vdv + i * 64) * 40 + vtc * 8) = vst[i];
            }
            __syncthreads();
            if (t + 1 < ntiles) {   // prefetch next tile (overlaps compute below)
                int kn = kb0 + 32;
#pragma unroll
                for (int i = 0; i < 2; i++) {
                    kst[i] = *(const short8*)(kbase + (size_t)(kn + kkey + i * 16) * NKV + kdc * 8);
                    vst[i] = *(const short8*)(vbase + (size_t)(vdv + i * 64) * TT + kn + vtc * 8);
                }
            }
            // ---- S^T = K * Q^T : C rows = keys (quad*4+r), cols = qrows (l15) ----
            floatx4 s[2][2];
            s[0][0] = floatx4{0.f,0.f,0.f,0.f}; s[0][1] = floatx4{0.f,0.f,0.f,0.f};
            s[1][0] = floatx4{0.f,0.f,0.f,0.f}; s[1][1] = floatx4{0.f,0.f,0.f,0.f};
#pragma unroll
            for (int ks = 0; ks < 4; ks++) {
                short8 kf0 = *(const short8*)(Ks + l15 * 136 + ks * 32 + quad * 8);
                short8 kf1 = *(const short8*)(Ks + (16 + l15) * 136 + ks * 32 + quad * 8);
                s[0][0] = __builtin_amdgcn_mfma_f32_16x16x32_bf16(kf0, qf[0][ks], s[0][0], 0, 0, 0);
                s[0][1] = __builtin_amdgcn_mfma_f32_16x16x32_bf16(kf0, qf[1][ks], s[0][1], 0, 0, 0);
                s[1][0] = __builtin_amdgcn_mfma_f32_16x16x32_bf16(kf1, qf[0][ks], s[1][0], 0, 0, 0);
                s[1][1] = __builtin_amdgcn_mfma_f32_16x16x32_bf16(kf1, qf[1][ks], s[1][1], 0, 0, 0);
            }
            bool maskT = (t == ntiles - 1);   // only the diagonal tile needs masking
#pragma unroll
            for (int qc = 0; qc < 2; qc++) {
                int qrow = q0 + qc * 16 + l15;
                float p[8];
#pragma unroll
                for (int krt = 0; krt < 2; krt++)
#pragma unroll
                    for (int r = 0; r < 4; r++) {
                        float v = s[krt][qc][r] * scale2;
                        if (maskT && (kb0 + krt * 16 + quad * 4 + r > qrow)) v = -INFINITY;
                        p[krt * 4 + r] = v;
                    }
                float mx = p[0];
#pragma unroll
                for (int j = 1; j < 8; j++) mx = fmaxf(mx, p[j]);
                mx = fmaxf(mx, __shfl_xor(mx, 16));
                mx = fmaxf(mx, __shfl_xor(mx, 32));
                float mnew = fmaxf(m_[qc], mx);
                float al = exp2f(m_[qc] - mnew);
                float e[8], sum = 0.f;
#pragma unroll
                for (int j = 0; j < 8; j++) { e[j] = exp2f(p[j] - mnew); sum += e[j]; }
                sum += __shfl_xor(sum, 16);
                sum += __shfl_xor(sum, 32);
                l_[qc] = l_[qc] * al + sum;
                m_[qc] = mnew;
                // broadcast alpha from lane l15=quad*4+r for O (row-indexed) rescale
                float ar[4];
#pragma unroll
                for (int r = 0; r < 4; r++) ar[r] = __shfl(al, quad * 4 + r);
#pragma unroll
                for (int vt = 0; vt < 8; vt++)
#pragma unroll
                    for (int r = 0; r < 4; r++) O[qc][vt][r] *= ar[r];
                // pack P^T -> LDS as P[qrow][key] (bf16, round-to-nearest)
                bshort4 pw0, pw1;
#pragma unroll
                for (int r = 0; r < 4; r++) {
                    pw0[r] = (short)((__float_as_uint(e[r]) + 0x8000u) >> 16);
                    pw1[r] = (short)((__float_as_uint(e[4 + r]) + 0x8000u) >> 16);
                }
                *(bshort4*)(P + (qc * 16 + l15) * 40 + quad * 4) = pw0;
                *(bshort4*)(P + (qc * 16 + l15) * 40 + 16 + quad * 4) = pw1;
            }
            // ---- O += P * V^T : A = P (m=qrow), B = V^T (n=dv) ----
            short8 pf0 = *(const short8*)(P + l15 * 40 + quad * 8);
            short8 pf1 = *(const short8*)(P + (16 + l15) * 40 + quad * 8);
#pragma unroll
            for (int vt = 0; vt < 8; vt++) {
                short8 vf = *(const short8*)(Vs + (vt * 16 + l15) * 40 + quad * 8);
                O[0][vt] = __builtin_amdgcn_mfma_f32_16x16x32_bf16(pf0, vf, O[0][vt], 0, 0, 0);
                O[1][vt] = __builtin_amdgcn_mfma_f32_16x16x32_bf16(pf1, vf, O[1][vt], 0, 0, 0);
            }
        }
        // epilogue: O C-layout row = qrow (quad*4+r), col = dv (vt*16+l15)
#pragma unroll
        for (int qc = 0; qc < 2; qc++) {
            float lr[4];
#pragma unroll
            for (int r = 0; r < 4; r++) lr[r] = 1.0f / __shfl(l_[qc], quad * 4 + r);
#pragma unroll
            for (int r = 0; r < 4; r++) {
                size_t row = (size_t)(b * TT + q0 + qc * 16 + quad * 4 + r);
#pragma unroll
                for (int vt = 0; vt < 8; vt++)
                    ob[row * NQ + hq * DK + vt * 16 + l15] = f2bf(O[qc][vt][r] * lr[r]);
            }
        }
    }
}

extern "C" void kernel_launch(void* const* d_in, const int* in_sizes, int n_in,
                              void* d_out, int out_size, void* d_ws, size_t ws_size,
                              hipStream_t stream)
{
    const float* q  = (const float*)d_in[0];
    const float* k  = (const float*)d_in[1];
    const float* v  = (const float*)d_in[2];
    const float* wq = (const float*)d_in[3];
    const float* wk = (const float*)d_in[4];
    const float* wv = (const float*)d_in[5];
    const float* wo = (const float*)d_in[6];
    float* out   = (float*)d_out;                       // [2,2048,4096]
    float* cache = out + (size_t)MM * DD;               // [2,2048,8,256]

    char* ws = (char*)d_ws;
    float* cosT = (float*)ws;
    float* sinT = cosT + TT * 64;
    size_t off = 1u << 20;  // 1 MB
    const size_t SZ32 = (size_t)MM * DD * 2;   // 32 MB (bf16 4096x4096)
    const size_t SZ8  = (size_t)MM * NKV * 2;  // 8 MB  (bf16 4096x1024)
    uint16_t* wqT = (uint16_t*)(ws + off); off += SZ32;   // 4096x4096
    uint16_t* wkT = (uint16_t*)(ws + off); off += SZ8;    // 1024x4096
    uint16_t* wvT = (uint16_t*)(ws + off); off += SZ8;    // 1024x4096
    uint16_t* qb  = (uint16_t*)(ws + off); off += SZ32;
    uint16_t* kb  = (uint16_t*)(ws + off); off += SZ32;
    uint16_t* vb  = (uint16_t*)(ws + off); off += SZ32;
    uint16_t* khB = (uint16_t*)(ws + off); off += SZ8;
    uint16_t* vhB = (uint16_t*)(ws + off); off += SZ8;
    // aliases (stream-ordered reuse):
    uint16_t* vTr = wvT;  // after V GEMM done with wvT
    uint16_t* qhB = vb;   // after V GEMM done with vb
    uint16_t* woT = kb;   // after K GEMM done with kb
    uint16_t* obf = qb;   // after Q GEMM done with qb

    // 1. RoPE tables
    rope_tables_k<<<TT, 64, 0, stream>>>(cosT, sinT);
    // 2. weight convert/transpose (wq, wk, wv)
    wconv_k<<<dim3(NQ / 32, DD / 32), dim3(32, 8), 0, stream>>>(wq, wqT, DD, NQ);
    wconv_k<<<dim3(NKV / 32, DD / 32), dim3(32, 8), 0, stream>>>(wk, wkT, DD, NKV);
    wconv_k<<<dim3(NKV / 32, DD / 32), dim3(32, 8), 0, stream>>>(wv, wvT, DD, NKV);
    // 3. activation converts
    int n4 = MM * DD / 4;
    aconv_k<<<(n4 + 255) / 256, 256, 0, stream>>>((const float4*)q, (uint2*)qb, n4);
    aconv_k<<<(n4 + 255) / 256, 256, 0, stream>>>((const float4*)k, (uint2*)kb, n4);
    aconv_k<<<(n4 + 255) / 256, 256, 0, stream>>>((const float4*)v, (uint2*)vb, n4);
    // 4. V GEMM (writes vh bf16 + cache fp32)
    gemm_k<3><<<dim3(NKV / 128, MM / 128), 256, 0, stream>>>(vb, wvT, MM, NKV, DD, vhB, cache, cosT, sinT);
    // 5. K GEMM (RoPE; writes kh bf16 + cache fp32)
    gemm_k<2><<<dim3(NKV / 128, MM / 128), 256, 0, stream>>>(kb, wkT, MM, NKV, DD, khB, cache, cosT, sinT);
    // 6. Q GEMM (RoPE; writes qh bf16 into vb's space)
    gemm_k<1><<<dim3(NQ / 128, MM / 128), 256, 0, stream>>>(qb, wqT, MM, NQ, DD, qhB, nullptr, cosT, sinT);
    // 7. wo convert (into kb's space)
    wconv_k<<<dim3(DD / 32, DD / 32), dim3(32, 8), 0, stream>>>(wo, woT, DD, DD);
    // 8. V transpose (into wvT's space)
    vtrans_k<<<dim3(TT / 32, DK / 32, BB * HKV), dim3(32, 8), 0, stream>>>(vhB, vTr);
    // 9. attention (into qb's space): grid = (qtile pairs, kv heads, batch)
    attn_k<<<dim3(32, HKV, BB), 256, 0, stream>>>(qhB, khB, vTr, obf);
    // 10. output projection -> fp32 out
    gemm_k<4><<<dim3(DD / 128, MM / 128), 256, 0, stream>>>(obf, woT, MM, DD, DD, nullptr, out, cosT, sinT);
}